// Round 1
// baseline (253.535 us; speedup 1.0000x reference)
//
#include <hip/hip_runtime.h>
#include <hip/hip_bf16.h>

#define IN_F  4096
#define OUT_F 11008
#define SEQ   512
#define NOUT  4096

#define BM 128
#define BN 128
#define BK 32

typedef __attribute__((ext_vector_type(8))) short bf16x8;
typedef __attribute__((ext_vector_type(4))) float f32x4;
typedef __attribute__((ext_vector_type(4))) int   int4v;
typedef __attribute__((ext_vector_type(4))) float float4v;

union Pack8 { bf16x8 v; __hip_bfloat16 h[8]; };

// C = X[512,4096] @ W[11008,4096]^T + bias, W = bf16(int8code * row_scale)
// 128x128 tile, BK=32, 4 waves (2x2), each wave 64x64 = 4x4 fragments of 16x16x32.
__global__ __launch_bounds__(256) void qgemm_kernel(
    const float* __restrict__ X,
    const int*   __restrict__ Q,
    const float* __restrict__ scale,
    const float* __restrict__ bias,
    float* __restrict__ out)
{
    __shared__ __hip_bfloat16 sA[BM][BK];   // 8 KB
    __shared__ __hip_bfloat16 sB[BN][BK];   // 8 KB

    const int tid  = threadIdx.x;
    const int wave = tid >> 6;
    const int lane = tid & 63;
    const int col0 = blockIdx.x * BN;   // N (out_features)
    const int row0 = blockIdx.y * BM;   // M (seq)

    const int wm = (wave >> 1) * 64;    // wave sub-tile within block tile
    const int wn = (wave & 1) * 64;

    f32x4 acc[4][4] = {};               // 64 VGPR accumulator

    // Staging geometry: thread t handles row sr = t/2, 16 elements at k-offset sk.
    const int sr = tid >> 1;
    const int sk = (tid & 1) * 16;
    const float* aptr = X + (size_t)(row0 + sr) * IN_F + sk;
    const int*   bptr = Q + (size_t)(col0 + sr) * IN_F + sk;
    const float bscale = scale[col0 + sr];   // loop-invariant row scale

    // Prologue: load tile 0 into registers.
    float4v a0, a1, a2, a3;
    int4v   b0, b1, b2, b3;
    a0 = *(const float4v*)(aptr + 0);
    a1 = *(const float4v*)(aptr + 4);
    a2 = *(const float4v*)(aptr + 8);
    a3 = *(const float4v*)(aptr + 12);
    b0 = *(const int4v*)(bptr + 0);
    b1 = *(const int4v*)(bptr + 4);
    b2 = *(const int4v*)(bptr + 8);
    b3 = *(const int4v*)(bptr + 12);

    const int fr = lane & 15;           // fragment row/col within 16
    const int fk = (lane >> 4) * 8;     // fragment k base

    for (int k0 = 0; k0 < IN_F; k0 += BK) {
        __syncthreads();                 // all waves done reading LDS of prev iter

        // Convert staged registers -> bf16 -> LDS.
        Pack8 w0, w1, v0, v1;
        #pragma unroll
        for (int i = 0; i < 4; ++i) {
            w0.h[i]     = __float2bfloat16(a0[i]);
            w0.h[4 + i] = __float2bfloat16(a1[i]);
            w1.h[i]     = __float2bfloat16(a2[i]);
            w1.h[4 + i] = __float2bfloat16(a3[i]);
            v0.h[i]     = __float2bfloat16((float)b0[i] * bscale);
            v0.h[4 + i] = __float2bfloat16((float)b1[i] * bscale);
            v1.h[i]     = __float2bfloat16((float)b2[i] * bscale);
            v1.h[4 + i] = __float2bfloat16((float)b3[i] * bscale);
        }
        *(bf16x8*)&sA[sr][sk]     = w0.v;
        *(bf16x8*)&sA[sr][sk + 8] = w1.v;
        *(bf16x8*)&sB[sr][sk]     = v0.v;
        *(bf16x8*)&sB[sr][sk + 8] = v1.v;
        __syncthreads();

        // Issue next tile's global loads before the MFMA cluster (latency hiding).
        if (k0 + BK < IN_F) {
            a0 = *(const float4v*)(aptr + k0 + BK + 0);
            a1 = *(const float4v*)(aptr + k0 + BK + 4);
            a2 = *(const float4v*)(aptr + k0 + BK + 8);
            a3 = *(const float4v*)(aptr + k0 + BK + 12);
            b0 = *(const int4v*)(bptr + k0 + BK + 0);
            b1 = *(const int4v*)(bptr + k0 + BK + 4);
            b2 = *(const int4v*)(bptr + k0 + BK + 8);
            b3 = *(const int4v*)(bptr + k0 + BK + 12);
        }

        // Fragments + MFMA.
        bf16x8 af[4], bfr[4];
        #pragma unroll
        for (int mi = 0; mi < 4; ++mi)
            af[mi] = *(const bf16x8*)&sA[wm + mi * 16 + fr][fk];
        #pragma unroll
        for (int ni = 0; ni < 4; ++ni)
            bfr[ni] = *(const bf16x8*)&sB[wn + ni * 16 + fr][fk];
        #pragma unroll
        for (int mi = 0; mi < 4; ++mi)
            #pragma unroll
            for (int ni = 0; ni < 4; ++ni)
                acc[mi][ni] = __builtin_amdgcn_mfma_f32_16x16x32_bf16(
                    af[mi], bfr[ni], acc[mi][ni], 0, 0, 0);
    }

    // Epilogue: C/D layout col=lane&15, row=(lane>>4)*4+reg.
    const int er = (lane >> 4) * 4;
    const int ec = lane & 15;
    #pragma unroll
    for (int ni = 0; ni < 4; ++ni) {
        const int gcol = col0 + wn + ni * 16 + ec;
        const float bv = bias[gcol];
        #pragma unroll
        for (int mi = 0; mi < 4; ++mi) {
            const int grow = row0 + wm + mi * 16 + er;
            #pragma unroll
            for (int r = 0; r < 4; ++r)
                out[(size_t)(grow + r) * OUT_F + gcol] = acc[mi][ni][r] + bv;
        }
    }
}

// One block per outlier: last-wins dedup (matches overwrite semantics), then
// out[s,row] += (outlier - bf16(q*scale)) * bf16(x[s,col]) for all s.
__global__ __launch_bounds__(256) void outlier_fix_kernel(
    const float* __restrict__ X,
    const int*   __restrict__ Q,
    const float* __restrict__ scale,
    const float* __restrict__ outv,
    const int*   __restrict__ oidx,
    float* __restrict__ out)
{
    __shared__ int dup;
    const int i = blockIdx.x;
    const int row = oidx[2 * i];
    const int col = oidx[2 * i + 1];

    if (threadIdx.x == 0) dup = 0;
    __syncthreads();
    for (int j = i + 1 + threadIdx.x; j < NOUT; j += 256)
        if (oidx[2 * j] == row && oidx[2 * j + 1] == col) dup = 1;
    __syncthreads();
    if (dup) return;  // a later duplicate exists; it wins

    const float deq = __bfloat162float(
        __float2bfloat16((float)Q[(size_t)row * IN_F + col] * scale[row]));
    const float d = outv[i] - deq;

    for (int s = threadIdx.x; s < SEQ; s += 256) {
        const float xv = __bfloat162float(__float2bfloat16(X[(size_t)s * IN_F + col]));
        atomicAdd(out + (size_t)s * OUT_F + row, d * xv);
    }
}

extern "C" void kernel_launch(void* const* d_in, const int* in_sizes, int n_in,
                              void* d_out, int out_size, void* d_ws, size_t ws_size,
                              hipStream_t stream) {
    const float* x    = (const float*)d_in[0];
    const int*   q    = (const int*)d_in[1];
    const float* qs   = (const float*)d_in[2];
    const float* qo   = (const float*)d_in[3];
    const int*   qi   = (const int*)d_in[4];
    const float* bias = (const float*)d_in[5];
    float* out = (float*)d_out;

    dim3 grid(OUT_F / BN, SEQ / BM);   // 86 x 4 = 344 blocks
    qgemm_kernel<<<grid, 256, 0, stream>>>(x, q, qs, bias, out);
    outlier_fix_kernel<<<NOUT, 256, 0, stream>>>(x, q, qs, qo, qi, out);
}

// Round 2
// 214.277 us; speedup vs baseline: 1.1832x; 1.1832x over previous
//
#include <hip/hip_runtime.h>
#include <hip/hip_bf16.h>

#define IN_F  4096
#define OUT_F 11008
#define SEQ   512
#define NOUT  4096

#define BM 128
#define BN 64
#define BK 32
#define LDK (BK + 4)           // +4 bf16 pad: row stride 72B -> 16 distinct start banks, conflict-free ds_read_b128
#define NBLK (OUT_F / BN)      // 172
#define MBLK (SEQ / BM)        // 4
#define NWG  (NBLK * MBLK)     // 688 = 8 * 86 -> bijective XCD swizzle

typedef __attribute__((ext_vector_type(8))) short bf16x8;
typedef __attribute__((ext_vector_type(4))) float f32x4;
typedef __attribute__((ext_vector_type(4))) int   int4v;
typedef __attribute__((ext_vector_type(4))) float float4v;

union Pack8 { bf16x8 v; __hip_bfloat16 h[8]; };

// Fully fused: C = X @ W^T + bias with W = bf16(int8 * row_scale), outlier
// overwrite applied as a rank-1 delta in the epilogue (block exclusively owns
// its out tile -> plain read-modify-write, no atomics).
__global__ __launch_bounds__(256) void qgemm_fused(
    const float* __restrict__ X,
    const int*   __restrict__ Q,
    const float* __restrict__ scale,
    const float* __restrict__ outv,
    const int*   __restrict__ oidx,
    const float* __restrict__ bias,
    float* __restrict__ out)
{
    __shared__ __hip_bfloat16 sA[BM][LDK];   // 9216 B
    __shared__ __hip_bfloat16 sB[BN][LDK];   // 4608 B
    __shared__ int list[256];
    __shared__ int lcount;
    __shared__ int dupflag;

    const int tid  = threadIdx.x;
    const int wave = tid >> 6;
    const int lane = tid & 63;

    // XCD-aware swizzle: XCD k owns tiles t = k*86 .. k*86+85. Within an XCD
    // the 4 M-blocks of one N-panel are consecutive -> Q panel (1MB) L2 reuse.
    const int lin = blockIdx.x;
    const int t = (lin & 7) * (NWG / 8) + (lin >> 3);
    const int col0 = (t >> 2) * BN;    // N (out_features) panel
    const int row0 = (t & 3) * BM;     // M (seq) panel

    const int wm = (wave >> 1) * 64;   // wave sub-tile: 64x32
    const int wn = (wave & 1) * 32;

    f32x4 acc[4][2] = {};

    // Staging geometry. A: 128 rows x 32 k, 16 elems/thread. B: 64 x 32, 8/thread.
    const int sra = tid >> 1, ska = (tid & 1) * 16;
    const int srb = tid >> 2, skb = (tid & 3) * 8;
    const float* aptr = X + (size_t)(row0 + sra) * IN_F + ska;
    const int*   bptr = Q + (size_t)(col0 + srb) * IN_F + skb;
    const float bscale = scale[col0 + srb];

    // Prologue: tile 0 into registers.
    float4v a0 = *(const float4v*)(aptr + 0);
    float4v a1 = *(const float4v*)(aptr + 4);
    float4v a2 = *(const float4v*)(aptr + 8);
    float4v a3 = *(const float4v*)(aptr + 12);
    int4v   b0 = *(const int4v*)(bptr + 0);
    int4v   b1 = *(const int4v*)(bptr + 4);

    const int fr = lane & 15;
    const int fk = (lane >> 4) * 8;

    for (int k0 = 0; k0 < IN_F; k0 += BK) {
        __syncthreads();
        // Convert staged regs -> bf16 -> LDS.
        Pack8 w0, w1, v0;
        #pragma unroll
        for (int i = 0; i < 4; ++i) {
            w0.h[i]     = __float2bfloat16(a0[i]);
            w0.h[4 + i] = __float2bfloat16(a1[i]);
            w1.h[i]     = __float2bfloat16(a2[i]);
            w1.h[4 + i] = __float2bfloat16(a3[i]);
            v0.h[i]     = __float2bfloat16((float)b0[i] * bscale);
            v0.h[4 + i] = __float2bfloat16((float)b1[i] * bscale);
        }
        *(bf16x8*)&sA[sra][ska]     = w0.v;
        *(bf16x8*)&sA[sra][ska + 8] = w1.v;
        *(bf16x8*)&sB[srb][skb]     = v0.v;
        __syncthreads();

        // Issue next tile's global loads before the MFMA cluster.
        if (k0 + BK < IN_F) {
            a0 = *(const float4v*)(aptr + k0 + BK + 0);
            a1 = *(const float4v*)(aptr + k0 + BK + 4);
            a2 = *(const float4v*)(aptr + k0 + BK + 8);
            a3 = *(const float4v*)(aptr + k0 + BK + 12);
            b0 = *(const int4v*)(bptr + k0 + BK + 0);
            b1 = *(const int4v*)(bptr + k0 + BK + 4);
        }

        bf16x8 af[4], bfr[2];
        #pragma unroll
        for (int mi = 0; mi < 4; ++mi)
            af[mi] = *(const bf16x8*)&sA[wm + mi * 16 + fr][fk];
        #pragma unroll
        for (int ni = 0; ni < 2; ++ni)
            bfr[ni] = *(const bf16x8*)&sB[wn + ni * 16 + fr][fk];
        #pragma unroll
        for (int mi = 0; mi < 4; ++mi)
            #pragma unroll
            for (int ni = 0; ni < 2; ++ni)
                acc[mi][ni] = __builtin_amdgcn_mfma_f32_16x16x32_bf16(
                    af[mi], bfr[ni], acc[mi][ni], 0, 0, 0);
    }

    // Epilogue: C/D layout col=lane&15, row=(lane>>4)*4+reg.
    const int er = (lane >> 4) * 4;
    const int ec = lane & 15;
    #pragma unroll
    for (int ni = 0; ni < 2; ++ni) {
        const int gcol = col0 + wn + ni * 16 + ec;
        const float bv = bias[gcol];
        #pragma unroll
        for (int mi = 0; mi < 4; ++mi) {
            const int grow = row0 + wm + mi * 16 + er;
            #pragma unroll
            for (int r = 0; r < 4; ++r)
                out[(size_t)(grow + r) * OUT_F + gcol] = acc[mi][ni][r] + bv;
        }
    }
    __syncthreads();   // all tile stores visible to this block before fix-up

    // Outlier fix-up: for each outlier (orow,ocol) with orow in this N-panel:
    // out[s, orow] += (outlier - bf16(q*scale)) * x[s, ocol], s in M-panel.
    // Chunked scan (list <= 256, cannot overflow). Later-duplicate wins:
    // skip an entry iff a duplicate with larger index exists (order-indep).
    for (int c = 0; c < NOUT / 256; ++c) {
        if (tid == 0) lcount = 0;
        __syncthreads();
        {
            const int j = c * 256 + tid;
            const int r = oidx[2 * j];
            if (r >= col0 && r < col0 + BN) {
                int p = atomicAdd(&lcount, 1);
                list[p] = j;
            }
        }
        __syncthreads();
        const int nm = lcount;
        for (int u = 0; u < nm; ++u) {
            const int ju   = list[u];
            const int orow = oidx[2 * ju];
            const int ocol = oidx[2 * ju + 1];
            if (tid == 0) dupflag = 0;
            __syncthreads();
            for (int j2 = ju + 1 + tid; j2 < NOUT; j2 += 256)
                if (oidx[2 * j2] == orow && oidx[2 * j2 + 1] == ocol) dupflag = 1;
            __syncthreads();
            if (!dupflag && tid < BM) {
                const float deq = __bfloat162float(__float2bfloat16(
                    (float)Q[(size_t)orow * IN_F + ocol] * scale[orow]));
                const float d = outv[ju] - deq;
                const int grow = row0 + tid;
                out[(size_t)grow * OUT_F + orow] += d * X[(size_t)grow * IN_F + ocol];
            }
            __syncthreads();
        }
    }
}

extern "C" void kernel_launch(void* const* d_in, const int* in_sizes, int n_in,
                              void* d_out, int out_size, void* d_ws, size_t ws_size,
                              hipStream_t stream) {
    const float* x    = (const float*)d_in[0];
    const int*   q    = (const int*)d_in[1];
    const float* qs   = (const float*)d_in[2];
    const float* qo   = (const float*)d_in[3];
    const int*   qi   = (const int*)d_in[4];
    const float* bias = (const float*)d_in[5];
    float* out = (float*)d_out;

    qgemm_fused<<<dim3(NWG), 256, 0, stream>>>(x, q, qs, qo, qi, bias, out);
}